// Round 9
// baseline (233.146 us; speedup 1.0000x reference)
//
#include <hip/hip_runtime.h>
#include <hip/hip_cooperative_groups.h>
#include <hip/hip_bf16.h>
#include <math.h>

typedef unsigned short ushort_t;
typedef __attribute__((ext_vector_type(8))) short short8;
typedef __attribute__((ext_vector_type(4))) short short4v;
typedef __attribute__((ext_vector_type(4))) float float4v;

#define NN 4096
#define BB 4
#define CC 64
#define ICH 32

// workspace layout (float offsets), splits chosen at launch from ws_size:
// QB 0..262144, KB ..524288, VT ..786432 (ushort views)
// OP = 786432, size splits*524288 ; LS after OP, size splits*16384 ; SP after.
#define OFF_QB 0
#define OFF_KB 262144
#define OFF_VT 524288
#define OFF_OP 786432

static __device__ __forceinline__ ushort_t f2b(float f) {
  union { float f; unsigned u; } v;
  v.f = f;
  return (ushort_t)((v.u + 0x8000u) >> 16);
}
static __device__ __forceinline__ unsigned pack2(float x, float y) {
  return (unsigned)f2b(x) | ((unsigned)f2b(y) << 16);
}
// load 8 consecutive fp32 -> bf16x8 frag
static __device__ __forceinline__ short8 cvt8(const float* p) {
  float4 a = *(const float4*)p;
  float4 b = *(const float4*)(p + 4);
  short8 r;
  r[0] = (short)f2b(a.x); r[1] = (short)f2b(a.y);
  r[2] = (short)f2b(a.z); r[3] = (short)f2b(a.w);
  r[4] = (short)f2b(b.x); r[5] = (short)f2b(b.y);
  r[6] = (short)f2b(b.z); r[7] = (short)f2b(b.w);
  return r;
}

// ---------------------------------------------------------------------------
// Kernel 1: projections via MFMA (unchanged from R8 - verified).
// ---------------------------------------------------------------------------
__global__ __launch_bounds__(256) void proj_kernel(
    const float* __restrict__ xt, const float* __restrict__ xo,
    const float* __restrict__ gw, const float* __restrict__ gb,
    const float* __restrict__ tw, const float* __restrict__ tb,
    const float* __restrict__ pw, const float* __restrict__ pb,
    ushort_t* __restrict__ Qb, ushort_t* __restrict__ Kb,
    ushort_t* __restrict__ Vt) {
  __shared__ ushort_t vt_l[ICH * 68];

  int t = threadIdx.x;
  int wv = t >> 6, lane = t & 63, l15 = lane & 15, quad = lane >> 4;
  int b = blockIdx.y;
  int n0w = blockIdx.x * 64 + wv * 16;

  const float* xrt = xt + ((size_t)(n0w + l15) * BB + b) * CC;
  const float* xro = xo + ((size_t)(n0w + l15) * BB + b) * CC;
  short8 at0 = cvt8(xrt + quad * 8);
  short8 at1 = cvt8(xrt + 32 + quad * 8);
  short8 ao0 = cvt8(xro + quad * 8);
  short8 ao1 = cvt8(xro + 32 + quad * 8);

#pragma unroll
  for (int h = 0; h < 2; h++) {
    int i = h * 16 + l15;
    {
      short8 b0 = cvt8(tw + (size_t)i * CC + quad * 8);
      short8 b1 = cvt8(tw + (size_t)i * CC + 32 + quad * 8);
      float bias = tb[i];
      float4v acc = {bias, bias, bias, bias};
      acc = __builtin_amdgcn_mfma_f32_16x16x32_bf16(at0, b0, acc, 0, 0, 0);
      acc = __builtin_amdgcn_mfma_f32_16x16x32_bf16(at1, b1, acc, 0, 0, 0);
#pragma unroll
      for (int r = 0; r < 4; r++)
        Kb[((size_t)b * NN + n0w + quad * 4 + r) * ICH + i] = f2b(acc[r]);
    }
    {
      short8 b0 = cvt8(pw + (size_t)i * CC + quad * 8);
      short8 b1 = cvt8(pw + (size_t)i * CC + 32 + quad * 8);
      float bias = pb[i];
      float4v acc = {bias, bias, bias, bias};
      acc = __builtin_amdgcn_mfma_f32_16x16x32_bf16(ao0, b0, acc, 0, 0, 0);
      acc = __builtin_amdgcn_mfma_f32_16x16x32_bf16(ao1, b1, acc, 0, 0, 0);
#pragma unroll
      for (int r = 0; r < 4; r++)
        Qb[((size_t)b * NN + n0w + quad * 4 + r) * ICH + i] = f2b(acc[r]);
    }
    {
      short8 b0 = cvt8(gw + (size_t)i * CC + quad * 8);
      short8 b1 = cvt8(gw + (size_t)i * CC + 32 + quad * 8);
      float bias = gb[i];
      float4v acc = {bias, bias, bias, bias};
      acc = __builtin_amdgcn_mfma_f32_16x16x32_bf16(at0, b0, acc, 0, 0, 0);
      acc = __builtin_amdgcn_mfma_f32_16x16x32_bf16(at1, b1, acc, 0, 0, 0);
#pragma unroll
      for (int r = 0; r < 4; r++)
        vt_l[(size_t)i * 68 + wv * 16 + quad * 4 + r] = f2b(acc[r]);
    }
  }
  __syncthreads();
  {
    int i = t & 31, seg = t >> 5;
    short8 v;
#pragma unroll
    for (int k = 0; k < 8; k++) v[k] = (short)vt_l[i * 68 + seg * 8 + k];
    *(short8*)(Vt + (size_t)(b * ICH + i) * NN + blockIdx.x * 64 + seg * 8) = v;
  }
}

// ---------------------------------------------------------------------------
// Kernel 2: MFMA attention partials.  S^T = MFMA(K,Q) so the C->A layout
// transform for PV is a pure-register 2-step butterfly (4 shfl_xor dwords):
//   step1 xor32 exchanges wrong-tile dword pairs, step2 xor16 exchanges
//   wrong-half pairs; result = A-frag P[q=l15][kr=quad*8+j].  No LDS.
// Unnormalized exp (scores bounded, clamp 60); splits additive.
// ---------------------------------------------------------------------------
__global__ __launch_bounds__(256) void attn_kernel(
    const ushort_t* __restrict__ Qb, const ushort_t* __restrict__ Kb,
    const ushort_t* __restrict__ Vt, float* __restrict__ OP,
    float* __restrict__ LS, int splits) {
  int t = threadIdx.x;
  int wv = t >> 6, lane = t & 63, l15 = lane & 15, quad = lane >> 4;
  int s = blockIdx.y, b = blockIdx.z;
  int q0 = blockIdx.x * 64 + wv * 16;
  int kspan = NN / splits;

  short8 qf = *(const short8*)(Qb + ((size_t)b * NN + q0 + l15) * ICH + quad * 8);

  float4v o0 = {0.f, 0.f, 0.f, 0.f};
  float4v o1 = {0.f, 0.f, 0.f, 0.f};
  float lsp = 0.f;

  const ushort_t* Kbb = Kb + (size_t)b * NN * ICH;
  const ushort_t* Vtb = Vt + (size_t)b * ICH * NN;
  int mbeg = s * kspan, mend = mbeg + kspan;

  const bool lowq = (quad < 2);
  const bool evenq = ((quad & 1) == 0);

  for (int m0 = mbeg; m0 < mend; m0 += 32) {
    const ushort_t* kp = Kbb + (size_t)(m0 + l15) * ICH + quad * 8;
    short8 kf0 = *(const short8*)(kp);
    short8 kf1 = *(const short8*)(kp + 16 * ICH);
    const ushort_t* vp = Vtb + (size_t)l15 * NN + m0 + quad * 8;
    short8 vf0 = *(const short8*)(vp);
    short8 vf1 = *(const short8*)(vp + 16 * NN);

    float4v z = {0.f, 0.f, 0.f, 0.f};
    // S^T tiles: row = kr_local = quad*4+r, col = q = l15
    float4v st0 = __builtin_amdgcn_mfma_f32_16x16x32_bf16(kf0, qf, z, 0, 0, 0);
    float4v st1 = __builtin_amdgcn_mfma_f32_16x16x32_bf16(kf1, qf, z, 0, 0, 0);

    float p0[4], p1[4];
#pragma unroll
    for (int r = 0; r < 4; r++) {
      p0[r] = __expf(fminf(st0[r], 60.f));
      p1[r] = __expf(fminf(st1[r], 60.f));
      lsp += p0[r] + p1[r];
    }
    // pack: d0,d1 = tile0 (kr 4q+0..3), d2,d3 = tile1 (kr 16+4q+0..3)
    unsigned d0 = pack2(p0[0], p0[1]);
    unsigned d1 = pack2(p0[2], p0[3]);
    unsigned d2 = pack2(p1[0], p1[1]);
    unsigned d3 = pack2(p1[2], p1[3]);
    // butterfly step 1: xor 32 (quad 0<->2, 1<->3)
    unsigned e0 = lowq ? d2 : d0, e1 = lowq ? d3 : d1;
    unsigned k0 = lowq ? d0 : d2, k1 = lowq ? d1 : d3;
    unsigned r0 = (unsigned)__shfl_xor((int)e0, 32, 64);
    unsigned r1 = (unsigned)__shfl_xor((int)e1, 32, 64);
    unsigned a0 = lowq ? k0 : r0;
    unsigned a1 = lowq ? k1 : r1;
    unsigned a2 = lowq ? r0 : k0;
    unsigned a3 = lowq ? r1 : k1;
    // butterfly step 2: xor 16 (quad 0<->1, 2<->3)
    unsigned f0 = evenq ? a2 : a0, f1 = evenq ? a3 : a1;
    unsigned g0 = evenq ? a0 : a2, g1 = evenq ? a1 : a3;
    unsigned s0w = (unsigned)__shfl_xor((int)f0, 16, 64);
    unsigned s1w = (unsigned)__shfl_xor((int)f1, 16, 64);
    unsigned w0 = evenq ? g0 : s0w;
    unsigned w1 = evenq ? g1 : s1w;
    unsigned w2 = evenq ? s0w : g0;
    unsigned w3 = evenq ? s1w : g1;

    union { unsigned u[4]; short8 s8; } pu;
    pu.u[0] = w0; pu.u[1] = w1; pu.u[2] = w2; pu.u[3] = w3;
    short8 pf = pu.s8;  // A-frag: P[q=l15][kr=quad*8+j]

    o0 = __builtin_amdgcn_mfma_f32_16x16x32_bf16(pf, vf0, o0, 0, 0, 0);
    o1 = __builtin_amdgcn_mfma_f32_16x16x32_bf16(pf, vf1, o1, 0, 0, 0);
  }

  // row sums: all 8 p's per lane belong to q=l15; reduce across quads
  lsp += __shfl_xor(lsp, 16, 64);
  lsp += __shfl_xor(lsp, 32, 64);

  size_t base = (size_t)(b * splits + s) * NN;
  if (quad == 0) LS[base + q0 + l15] = lsp;
#pragma unroll
  for (int r = 0; r < 4; r++) {
    int q = q0 + quad * 4 + r;
    float* op = OP + (base + q) * ICH;
    op[l15] = o0[r];
    op[16 + l15] = o1[r];
  }
}

// ---------------------------------------------------------------------------
// Kernel 3 (cooperative): combine splits + wz + BN stats + normalize +
// residual, one launch.  256 blocks (1/CU), WY tile held in LDS across the
// grid sync; every block recomputes final stats (deterministic fp64).
// ---------------------------------------------------------------------------
__global__ __launch_bounds__(256) void tail_kernel(
    const float* __restrict__ OP, const float* __restrict__ LS,
    const float* __restrict__ wz_w, const float* __restrict__ wz_b,
    const float* __restrict__ gamma, const float* __restrict__ beta,
    const float* __restrict__ xthis, float* __restrict__ SP,
    float* __restrict__ out, int splits) {
  __shared__ float yl[64 * 36];
  __shared__ float wyl[64 * 65];
  __shared__ float xl[64 * 65];
  __shared__ float lsum[64];
  __shared__ float red1[256], red2[256];
  __shared__ float abr[128];
  __shared__ double rd1[256], rd2[256];

  int b = blockIdx.y, n0 = blockIdx.x * 64, t = threadIdx.x;
  int blkid = b * 64 + blockIdx.x;

  if (t < 64) {
    float ssum = 0.f;
    for (int sp = 0; sp < splits; sp++)
      ssum += LS[(size_t)(b * splits + sp) * NN + n0 + t];
    lsum[t] = ssum;
  }
  __syncthreads();
#pragma unroll
  for (int it = 0; it < 8; it++) {
    int lin = it * 256 + t;
    int i = lin & 31, dn = lin >> 5;
    float sacc = 0.f;
    for (int sp = 0; sp < splits; sp++)
      sacc += OP[((size_t)(b * splits + sp) * NN + n0 + dn) * ICH + i];
    yl[dn * 36 + i] = sacc / lsum[dn];
  }
  __syncthreads();

  int c = t >> 2, sub = t & 3;
  float4 w4[8];
#pragma unroll
  for (int j = 0; j < 8; j++) w4[j] = ((const float4*)(wz_w + c * ICH))[j];
  float bc = wz_b[c];
  float s1 = 0.f, s2 = 0.f;
#pragma unroll
  for (int d = 0; d < 16; d++) {
    int dn = sub * 16 + d;
    const float4* y4 = (const float4*)(yl + dn * 36);
    float acc = bc;
#pragma unroll
    for (int j = 0; j < 8; j++) {
      float4 y = y4[j];
      acc += w4[j].x * y.x + w4[j].y * y.y + w4[j].z * y.z + w4[j].w * y.w;
    }
    wyl[c * 65 + dn] = acc;
    s1 += acc;
    s2 += acc * acc;
  }
  red1[t] = s1;
  red2[t] = s2;
  __syncthreads();
  if (t < 64) {
    float a1 = red1[t * 4] + red1[t * 4 + 1] + red1[t * 4 + 2] + red1[t * 4 + 3];
    float a2 = red2[t * 4] + red2[t * 4 + 1] + red2[t * 4 + 2] + red2[t * 4 + 3];
    SP[(size_t)blkid * 64 + t] = a1;
    SP[16384 + (size_t)blkid * 64 + t] = a2;
  }
  __threadfence();
  cooperative_groups::this_grid().sync();

  // every block: final deterministic stats from SP
  {
    int cc = t & 63, part = t >> 6;
    double d1 = 0.0, d2 = 0.0;
    for (int k = part * 64; k < part * 64 + 64; k++) {
      d1 += (double)SP[(size_t)k * 64 + cc];
      d2 += (double)SP[16384 + (size_t)k * 64 + cc];
    }
    rd1[t] = d1;
    rd2[t] = d2;
  }
  __syncthreads();
  if (t < 64) {
    double a1 = rd1[t] + rd1[64 + t] + rd1[128 + t] + rd1[192 + t];
    double a2 = rd2[t] + rd2[64 + t] + rd2[128 + t] + rd2[192 + t];
    double inv = 1.0 / (double)(BB * NN);
    double mean = a1 * inv;
    double var = a2 * inv - mean * mean;
    if (var < 0.0) var = 0.0;
    double rstd = 1.0 / sqrt(var + 1e-5);
    float A = gamma[t] * (float)rstd;
    abr[t] = A;
    abr[64 + t] = beta[t] - (float)mean * A;
  }
#pragma unroll
  for (int it = 0; it < 16; it++) {
    int lin = it * 256 + t;
    int ci = lin & 63, dn = lin >> 6;
    xl[dn * 65 + ci] = xthis[((size_t)(n0 + dn) * BB + b) * CC + ci];
  }
  __syncthreads();
#pragma unroll
  for (int it = 0; it < 16; it++) {
    int lin = it * 256 + t;
    int ci = lin >> 6, dn = lin & 63;
    out[((size_t)(b * CC + ci)) * NN + n0 + dn] =
        wyl[ci * 65 + dn] * abr[ci] + abr[64 + ci] + xl[dn * 65 + ci];
  }
}

// ---------------------------------------------------------------------------
extern "C" void kernel_launch(void* const* d_in, const int* in_sizes, int n_in,
                              void* d_out, int out_size, void* d_ws,
                              size_t ws_size, hipStream_t stream) {
  const float* x_this = (const float*)d_in[0];
  const float* x_other = (const float*)d_in[1];
  const float* g_w = (const float*)d_in[2];
  const float* g_b = (const float*)d_in[3];
  const float* th_w = (const float*)d_in[4];
  const float* th_b = (const float*)d_in[5];
  const float* ph_w = (const float*)d_in[6];
  const float* ph_b = (const float*)d_in[7];
  const float* wz_w = (const float*)d_in[8];
  const float* wz_b = (const float*)d_in[9];
  const float* gamma = (const float*)d_in[10];
  const float* beta = (const float*)d_in[11];
  float* out = (float*)d_out;

  float* ws = (float*)d_ws;
  ushort_t* Qb = (ushort_t*)(ws + OFF_QB);
  ushort_t* Kb = (ushort_t*)(ws + OFF_KB);
  ushort_t* Vt = (ushort_t*)(ws + OFF_VT);

  int splits = 8;
  // floats needed: 786432 + splits*524288 (OP) + splits*16384 (LS) + 32768 (SP)
  while (splits > 1 &&
         ws_size < (size_t)(786432 + (size_t)splits * 540672 + 32768) * 4)
    splits >>= 1;
  float* OP = ws + OFF_OP;
  float* LS = OP + (size_t)splits * 524288;
  float* SP = LS + (size_t)splits * 16384;

  hipLaunchKernelGGL(proj_kernel, dim3(NN / 64, BB), dim3(256), 0, stream,
                     x_this, x_other, g_w, g_b, th_w, th_b, ph_w, ph_b,
                     Qb, Kb, Vt);
  hipLaunchKernelGGL(attn_kernel, dim3(NN / 64, splits, BB), dim3(256), 0,
                     stream, Qb, Kb, Vt, OP, LS, splits);
  void* args[] = {&OP, &LS, &wz_w, &wz_b, &gamma, &beta, &x_this, &SP, &out,
                  &splits};
  hipLaunchCooperativeKernel((const void*)tail_kernel, dim3(NN / 64, BB),
                             dim3(256), args, 0, stream);
}

// Round 10
// 154.920 us; speedup vs baseline: 1.5049x; 1.5049x over previous
//
#include <hip/hip_runtime.h>
#include <hip/hip_bf16.h>
#include <math.h>

typedef unsigned short ushort_t;
typedef __attribute__((ext_vector_type(8))) short short8;
typedef __attribute__((ext_vector_type(4))) float float4v;

#define NN 4096
#define BB 4
#define CC 64
#define ICH 32

// workspace layout (float offsets); splits=4: total ~11.9 MB
#define OFF_QB 0
#define OFF_KB 262144
#define OFF_VT 524288
#define OFF_OP 786432

static __device__ __forceinline__ ushort_t f2b(float f) {
  union { float f; unsigned u; } v;
  v.f = f;
  return (ushort_t)((v.u + 0x8000u) >> 16);
}
static __device__ __forceinline__ unsigned pack2(float x, float y) {
  return (unsigned)f2b(x) | ((unsigned)f2b(y) << 16);
}
static __device__ __forceinline__ short8 cvt8(const float* p) {
  float4 a = *(const float4*)p;
  float4 b = *(const float4*)(p + 4);
  short8 r;
  r[0] = (short)f2b(a.x); r[1] = (short)f2b(a.y);
  r[2] = (short)f2b(a.z); r[3] = (short)f2b(a.w);
  r[4] = (short)f2b(b.x); r[5] = (short)f2b(b.y);
  r[6] = (short)f2b(b.z); r[7] = (short)f2b(b.w);
  return r;
}

// ---------------------------------------------------------------------------
// Kernel 1: projections via MFMA, one projection per blockIdx.z (3x blocks).
// z=0: theta(x_this)->Kb ; z=1: phi(x_other)->Qb ; z=2: g(x_this)->Vt.
// ---------------------------------------------------------------------------
__global__ __launch_bounds__(256) void proj_kernel(
    const float* __restrict__ xt, const float* __restrict__ xo,
    const float* __restrict__ gw, const float* __restrict__ gb,
    const float* __restrict__ tw, const float* __restrict__ tb,
    const float* __restrict__ pw, const float* __restrict__ pb,
    ushort_t* __restrict__ Qb, ushort_t* __restrict__ Kb,
    ushort_t* __restrict__ Vt) {
  __shared__ ushort_t vt_l[ICH * 68];

  int t = threadIdx.x;
  int wv = t >> 6, lane = t & 63, l15 = lane & 15, quad = lane >> 4;
  int b = blockIdx.y, z = blockIdx.z;
  int n0w = blockIdx.x * 64 + wv * 16;

  const float* xsrc = (z == 1) ? xo : xt;
  const float* W = (z == 0) ? tw : (z == 1) ? pw : gw;
  const float* Bv = (z == 0) ? tb : (z == 1) ? pb : gb;
  ushort_t* dst = (z == 0) ? Kb : Qb;

  const float* xr = xsrc + ((size_t)(n0w + l15) * BB + b) * CC;
  short8 a0 = cvt8(xr + quad * 8);
  short8 a1 = cvt8(xr + 32 + quad * 8);

#pragma unroll
  for (int h = 0; h < 2; h++) {
    int i = h * 16 + l15;
    short8 b0 = cvt8(W + (size_t)i * CC + quad * 8);
    short8 b1 = cvt8(W + (size_t)i * CC + 32 + quad * 8);
    float bias = Bv[i];
    float4v acc = {bias, bias, bias, bias};
    acc = __builtin_amdgcn_mfma_f32_16x16x32_bf16(a0, b0, acc, 0, 0, 0);
    acc = __builtin_amdgcn_mfma_f32_16x16x32_bf16(a1, b1, acc, 0, 0, 0);
    if (z < 2) {
#pragma unroll
      for (int r = 0; r < 4; r++)
        dst[((size_t)b * NN + n0w + quad * 4 + r) * ICH + i] = f2b(acc[r]);
    } else {
#pragma unroll
      for (int r = 0; r < 4; r++)
        vt_l[(size_t)i * 68 + wv * 16 + quad * 4 + r] = f2b(acc[r]);
    }
  }
  if (z == 2) {
    __syncthreads();
    int i = t & 31, seg = t >> 5;
    short8 v;
#pragma unroll
    for (int k = 0; k < 8; k++) v[k] = (short)vt_l[i * 68 + seg * 8 + k];
    *(short8*)(Vt + (size_t)(b * ICH + i) * NN + blockIdx.x * 64 + seg * 8) = v;
  }
}

// ---------------------------------------------------------------------------
// Kernel 2: MFMA attention partials, register-butterfly C->A transform
// (verified bit-exact in R9).  No LDS.  Unnormalized exp, additive splits.
// ---------------------------------------------------------------------------
__global__ __launch_bounds__(256) void attn_kernel(
    const ushort_t* __restrict__ Qb, const ushort_t* __restrict__ Kb,
    const ushort_t* __restrict__ Vt, float* __restrict__ OP,
    float* __restrict__ LS, int splits) {
  int t = threadIdx.x;
  int wv = t >> 6, lane = t & 63, l15 = lane & 15, quad = lane >> 4;
  int s = blockIdx.y, b = blockIdx.z;
  int q0 = blockIdx.x * 64 + wv * 16;
  int kspan = NN / splits;

  short8 qf = *(const short8*)(Qb + ((size_t)b * NN + q0 + l15) * ICH + quad * 8);

  float4v o0 = {0.f, 0.f, 0.f, 0.f};
  float4v o1 = {0.f, 0.f, 0.f, 0.f};
  float lsp = 0.f;

  const ushort_t* Kbb = Kb + (size_t)b * NN * ICH;
  const ushort_t* Vtb = Vt + (size_t)b * ICH * NN;
  int mbeg = s * kspan, mend = mbeg + kspan;

  const bool lowq = (quad < 2);
  const bool evenq = ((quad & 1) == 0);

  for (int m0 = mbeg; m0 < mend; m0 += 32) {
    const ushort_t* kp = Kbb + (size_t)(m0 + l15) * ICH + quad * 8;
    short8 kf0 = *(const short8*)(kp);
    short8 kf1 = *(const short8*)(kp + 16 * ICH);
    const ushort_t* vp = Vtb + (size_t)l15 * NN + m0 + quad * 8;
    short8 vf0 = *(const short8*)(vp);
    short8 vf1 = *(const short8*)(vp + 16 * NN);

    float4v z = {0.f, 0.f, 0.f, 0.f};
    float4v st0 = __builtin_amdgcn_mfma_f32_16x16x32_bf16(kf0, qf, z, 0, 0, 0);
    float4v st1 = __builtin_amdgcn_mfma_f32_16x16x32_bf16(kf1, qf, z, 0, 0, 0);

    float p0[4], p1[4];
#pragma unroll
    for (int r = 0; r < 4; r++) {
      p0[r] = __expf(fminf(st0[r], 60.f));
      p1[r] = __expf(fminf(st1[r], 60.f));
      lsp += p0[r] + p1[r];
    }
    unsigned d0 = pack2(p0[0], p0[1]);
    unsigned d1 = pack2(p0[2], p0[3]);
    unsigned d2 = pack2(p1[0], p1[1]);
    unsigned d3 = pack2(p1[2], p1[3]);
    unsigned e0 = lowq ? d2 : d0, e1 = lowq ? d3 : d1;
    unsigned k0 = lowq ? d0 : d2, k1 = lowq ? d1 : d3;
    unsigned r0 = (unsigned)__shfl_xor((int)e0, 32, 64);
    unsigned r1 = (unsigned)__shfl_xor((int)e1, 32, 64);
    unsigned a0 = lowq ? k0 : r0;
    unsigned a1 = lowq ? k1 : r1;
    unsigned a2 = lowq ? r0 : k0;
    unsigned a3 = lowq ? r1 : k1;
    unsigned f0 = evenq ? a2 : a0, f1 = evenq ? a3 : a1;
    unsigned g0 = evenq ? a0 : a2, g1 = evenq ? a1 : a3;
    unsigned s0w = (unsigned)__shfl_xor((int)f0, 16, 64);
    unsigned s1w = (unsigned)__shfl_xor((int)f1, 16, 64);
    unsigned w0 = evenq ? g0 : s0w;
    unsigned w1 = evenq ? g1 : s1w;
    unsigned w2 = evenq ? s0w : g0;
    unsigned w3 = evenq ? s1w : g1;

    union { unsigned u[4]; short8 s8; } pu;
    pu.u[0] = w0; pu.u[1] = w1; pu.u[2] = w2; pu.u[3] = w3;
    short8 pf = pu.s8;

    o0 = __builtin_amdgcn_mfma_f32_16x16x32_bf16(pf, vf0, o0, 0, 0, 0);
    o1 = __builtin_amdgcn_mfma_f32_16x16x32_bf16(pf, vf1, o1, 0, 0, 0);
  }

  lsp += __shfl_xor(lsp, 16, 64);
  lsp += __shfl_xor(lsp, 32, 64);

  size_t base = (size_t)(b * splits + s) * NN;
  if (quad == 0) LS[base + q0 + l15] = lsp;
#pragma unroll
  for (int r = 0; r < 4; r++) {
    int q = q0 + quad * 4 + r;
    float* op = OP + (base + q) * ICH;
    op[l15] = o0[r];
    op[16 + l15] = o1[r];
  }
}

// ---------------------------------------------------------------------------
// Kernel 3: combine splits + wz + BN stat partials (R8-proven).
// ---------------------------------------------------------------------------
__global__ __launch_bounds__(256) void wz_kernel(
    const float* __restrict__ OP, const float* __restrict__ LS,
    const float* __restrict__ wz_w, const float* __restrict__ wz_b,
    float* __restrict__ WY, float* __restrict__ SP, int splits) {
  __shared__ float yl[64 * 36];
  __shared__ float lsum[64];
  __shared__ float red1[256], red2[256];

  int b = blockIdx.y, n0 = blockIdx.x * 64, t = threadIdx.x;
  int blkid = b * 64 + blockIdx.x;

  if (t < 64) {
    float ssum = 0.f;
    for (int sp = 0; sp < splits; sp++)
      ssum += LS[(size_t)(b * splits + sp) * NN + n0 + t];
    lsum[t] = ssum;
  }
  __syncthreads();
#pragma unroll
  for (int it = 0; it < 8; it++) {
    int lin = it * 256 + t;
    int i = lin & 31, dn = lin >> 5;
    float sacc = 0.f;
    for (int sp = 0; sp < splits; sp++)
      sacc += OP[((size_t)(b * splits + sp) * NN + n0 + dn) * ICH + i];
    yl[dn * 36 + i] = sacc / lsum[dn];
  }
  __syncthreads();

  int c = t >> 2, sub = t & 3;
  float4 w4[8];
#pragma unroll
  for (int j = 0; j < 8; j++) w4[j] = ((const float4*)(wz_w + c * ICH))[j];
  float bc = wz_b[c];
  float s1 = 0.f, s2 = 0.f;
#pragma unroll
  for (int d = 0; d < 16; d++) {
    int dn = sub * 16 + d;
    const float4* y4 = (const float4*)(yl + dn * 36);
    float acc = bc;
#pragma unroll
    for (int j = 0; j < 8; j++) {
      float4 y = y4[j];
      acc += w4[j].x * y.x + w4[j].y * y.y + w4[j].z * y.z + w4[j].w * y.w;
    }
    WY[((size_t)(b * CC + c)) * NN + n0 + dn] = acc;
    s1 += acc;
    s2 += acc * acc;
  }
  red1[t] = s1;
  red2[t] = s2;
  __syncthreads();
  if (t < 64) {
    float a1 = red1[t * 4] + red1[t * 4 + 1] + red1[t * 4 + 2] + red1[t * 4 + 3];
    float a2 = red2[t * 4] + red2[t * 4 + 1] + red2[t * 4 + 2] + red2[t * 4 + 3];
    SP[(size_t)blkid * 64 + t] = a1;
    SP[16384 + (size_t)blkid * 64 + t] = a2;
  }
}

// ---------------------------------------------------------------------------
// Kernel 4: final BN stats, PARALLEL: one block per channel, deterministic
// LDS tree over the 256 block-partials.
// ---------------------------------------------------------------------------
__global__ __launch_bounds__(256) void stats_kernel(
    const float* __restrict__ SP, const float* __restrict__ gamma,
    const float* __restrict__ beta, float* __restrict__ AB) {
  __shared__ double r1[256], r2[256];
  int c = blockIdx.x, t = threadIdx.x;
  r1[t] = (double)SP[(size_t)t * 64 + c];
  r2[t] = (double)SP[16384 + (size_t)t * 64 + c];
  __syncthreads();
  for (int off = 128; off > 0; off >>= 1) {
    if (t < off) {
      r1[t] += r1[t + off];
      r2[t] += r2[t + off];
    }
    __syncthreads();
  }
  if (t == 0) {
    double inv = 1.0 / (double)(BB * NN);
    double mean = r1[0] * inv;
    double var = r2[0] * inv - mean * mean;
    if (var < 0.0) var = 0.0;
    double rstd = 1.0 / sqrt(var + 1e-5);
    float A = gamma[c] * (float)rstd;
    AB[c] = A;
    AB[64 + c] = beta[c] - (float)mean * A;
  }
}

// ---------------------------------------------------------------------------
// Kernel 5: normalize + residual -> fp32 out (B,C,N)  (R8-proven)
// ---------------------------------------------------------------------------
__global__ __launch_bounds__(256) void norm_kernel(
    const float* __restrict__ WY, const float* __restrict__ AB,
    const float* __restrict__ xthis, float* __restrict__ out) {
  __shared__ float xl[64 * 65];
  __shared__ float abr[128];
  int b = blockIdx.y, n0 = blockIdx.x * 64, t = threadIdx.x;
  if (t < 128) abr[t] = AB[t];
#pragma unroll
  for (int it = 0; it < 16; it++) {
    int lin = it * 256 + t;
    int c = lin & 63, dn = lin >> 6;
    xl[dn * 65 + c] = xthis[((size_t)(n0 + dn) * BB + b) * CC + c];
  }
  __syncthreads();
#pragma unroll
  for (int it = 0; it < 16; it++) {
    int lin = it * 256 + t;
    int c = lin >> 6, dn = lin & 63;
    size_t idx = ((size_t)(b * CC + c)) * NN + n0 + dn;
    out[idx] = WY[idx] * abr[c] + abr[64 + c] + xl[dn * 65 + c];
  }
}

// ---------------------------------------------------------------------------
extern "C" void kernel_launch(void* const* d_in, const int* in_sizes, int n_in,
                              void* d_out, int out_size, void* d_ws,
                              size_t ws_size, hipStream_t stream) {
  const float* x_this = (const float*)d_in[0];
  const float* x_other = (const float*)d_in[1];
  const float* g_w = (const float*)d_in[2];
  const float* g_b = (const float*)d_in[3];
  const float* th_w = (const float*)d_in[4];
  const float* th_b = (const float*)d_in[5];
  const float* ph_w = (const float*)d_in[6];
  const float* ph_b = (const float*)d_in[7];
  const float* wz_w = (const float*)d_in[8];
  const float* wz_b = (const float*)d_in[9];
  const float* gamma = (const float*)d_in[10];
  const float* beta = (const float*)d_in[11];
  float* out = (float*)d_out;

  float* ws = (float*)d_ws;
  ushort_t* Qb = (ushort_t*)(ws + OFF_QB);
  ushort_t* Kb = (ushort_t*)(ws + OFF_KB);
  ushort_t* Vt = (ushort_t*)(ws + OFF_VT);

  int splits = 4;
  while (splits > 1 &&
         ws_size < (size_t)(786432 + (size_t)splits * 540672 + 32768 +
                            1048576) * 4)
    splits >>= 1;
  float* OP = ws + OFF_OP;
  float* LS = OP + (size_t)splits * 524288;
  float* SP = LS + (size_t)splits * 16384;
  float* WY = SP + 32768;
  float* AB = WY + 1048576;  // needs 128 more floats of ws

  hipLaunchKernelGGL(proj_kernel, dim3(NN / 64, BB, 3), dim3(256), 0, stream,
                     x_this, x_other, g_w, g_b, th_w, th_b, ph_w, ph_b,
                     Qb, Kb, Vt);
  hipLaunchKernelGGL(attn_kernel, dim3(NN / 64, splits, BB), dim3(256), 0,
                     stream, Qb, Kb, Vt, OP, LS, splits);
  hipLaunchKernelGGL(wz_kernel, dim3(NN / 64, BB), dim3(256), 0, stream,
                     OP, LS, wz_w, wz_b, WY, SP, splits);
  hipLaunchKernelGGL(stats_kernel, dim3(CC), dim3(256), 0, stream,
                     SP, gamma, beta, AB);
  hipLaunchKernelGGL(norm_kernel, dim3(NN / 64, BB), dim3(256), 0, stream,
                     WY, AB, x_this, out);
}

// Round 11
// 145.735 us; speedup vs baseline: 1.5998x; 1.0630x over previous
//
#include <hip/hip_runtime.h>
#include <hip/hip_bf16.h>
#include <math.h>

typedef unsigned short ushort_t;
typedef __attribute__((ext_vector_type(8))) short short8;
typedef __attribute__((ext_vector_type(4))) float float4v;

#define NN 4096
#define BB 4
#define CC 64
#define ICH 32

#define OFF_QB 0
#define OFF_KB 262144
#define OFF_VT 524288
#define OFF_OP 786432

static __device__ __forceinline__ ushort_t f2b(float f) {
  union { float f; unsigned u; } v;
  v.f = f;
  return (ushort_t)((v.u + 0x8000u) >> 16);
}
static __device__ __forceinline__ unsigned pack2(float x, float y) {
  return (unsigned)f2b(x) | ((unsigned)f2b(y) << 16);
}
// 8 fp32 (from LDS) -> bf16x8 frag
static __device__ __forceinline__ short8 cvt8lds(const float* p) {
  short8 r;
#pragma unroll
  for (int j = 0; j < 8; j++) r[j] = (short)f2b(p[j]);
  return r;
}

// ---------------------------------------------------------------------------
// Kernel 1: projections via MFMA, one projection per blockIdx.z.
// x tile and W staged through LDS with coalesced global loads; outputs
// staged through LDS for 1KB-contiguous wave stores.
// z=0: theta(x_this)->Kb ; z=1: phi(x_other)->Qb ; z=2: g(x_this)->Vt.
// ---------------------------------------------------------------------------
__global__ __launch_bounds__(256) void proj_kernel(
    const float* __restrict__ xt, const float* __restrict__ xo,
    const float* __restrict__ gw, const float* __restrict__ gb,
    const float* __restrict__ tw, const float* __restrict__ tb,
    const float* __restrict__ pw, const float* __restrict__ pb,
    ushort_t* __restrict__ Qb, ushort_t* __restrict__ Kb,
    ushort_t* __restrict__ Vt) {
  __shared__ float xls[64 * 68];   // [n_local][c], pad 68
  __shared__ float wls[ICH * 68];  // [i][c], pad 68
  __shared__ float bls[ICH];
  __shared__ ushort_t ol[2304];    // z<2: [n64][i32 pad36]; z=2: [i32][n64 pad68]

  int t = threadIdx.x;
  int wv = t >> 6, lane = t & 63, l15 = lane & 15, quad = lane >> 4;
  int b = blockIdx.y, z = blockIdx.z;
  int n0 = blockIdx.x * 64;

  const float* xsrc = (z == 1) ? xo : xt;
  const float* W = (z == 0) ? tw : (z == 1) ? pw : gw;
  const float* Bv = (z == 0) ? tb : (z == 1) ? pb : gb;

  // stage x tile (64 rows x 64 ch), coalesced float4
#pragma unroll
  for (int it = 0; it < 4; it++) {
    int lin = it * 256 + t;       // 0..1023 float4s
    int row = lin >> 4, seg = lin & 15;
    float4 v = *(const float4*)(xsrc + ((size_t)(n0 + row) * BB + b) * CC + seg * 4);
    *(float4*)(xls + row * 68 + seg * 4) = v;
  }
  // stage W (32 x 64), coalesced
#pragma unroll
  for (int it = 0; it < 2; it++) {
    int lin = it * 256 + t;       // 0..511 float4s
    int row = lin >> 4, seg = lin & 15;
    float4 v = *(const float4*)(W + (size_t)row * CC + seg * 4);
    *(float4*)(wls + row * 68 + seg * 4) = v;
  }
  if (t < ICH) bls[t] = Bv[t];
  __syncthreads();

  // frags from LDS
  const float* xr = xls + (wv * 16 + l15) * 68;
  short8 a0 = cvt8lds(xr + quad * 8);
  short8 a1 = cvt8lds(xr + 32 + quad * 8);

#pragma unroll
  for (int h = 0; h < 2; h++) {
    int i = h * 16 + l15;
    short8 b0 = cvt8lds(wls + i * 68 + quad * 8);
    short8 b1 = cvt8lds(wls + i * 68 + 32 + quad * 8);
    float bias = bls[i];
    float4v acc = {bias, bias, bias, bias};
    acc = __builtin_amdgcn_mfma_f32_16x16x32_bf16(a0, b0, acc, 0, 0, 0);
    acc = __builtin_amdgcn_mfma_f32_16x16x32_bf16(a1, b1, acc, 0, 0, 0);
    if (z < 2) {
#pragma unroll
      for (int r = 0; r < 4; r++)
        ol[(wv * 16 + quad * 4 + r) * 36 + i] = f2b(acc[r]);
    } else {
#pragma unroll
      for (int r = 0; r < 4; r++)
        ol[i * 68 + wv * 16 + quad * 4 + r] = f2b(acc[r]);
    }
  }
  __syncthreads();

  if (z < 2) {
    ushort_t* dst = (z == 0) ? Kb : Qb;
    int row = t >> 2, seg = t & 3;
    short8 v;
#pragma unroll
    for (int k = 0; k < 8; k++) v[k] = (short)ol[row * 36 + seg * 8 + k];
    *(short8*)(dst + ((size_t)b * NN + n0 + row) * ICH + seg * 8) = v;
  } else {
    int i = t & 31, seg = t >> 5;
    short8 v;
#pragma unroll
    for (int k = 0; k < 8; k++) v[k] = (short)ol[i * 68 + seg * 8 + k];
    *(short8*)(Vt + (size_t)(b * ICH + i) * NN + n0 + seg * 8) = v;
  }
}

// ---------------------------------------------------------------------------
// Kernel 2: MFMA attention partials.  4 Q-frags per wave (64 q rows) so each
// K/V load feeds 4x the MFMA work (TA-path relief).  Register-butterfly
// C->A transform per frag (bit-exact verified R9/R10).  Unnormalized exp.
// ---------------------------------------------------------------------------
__global__ __launch_bounds__(256) void attn_kernel(
    const ushort_t* __restrict__ Qb, const ushort_t* __restrict__ Kb,
    const ushort_t* __restrict__ Vt, float* __restrict__ OP,
    float* __restrict__ LS, int splits) {
  int t = threadIdx.x;
  int wv = t >> 6, lane = t & 63, l15 = lane & 15, quad = lane >> 4;
  int s = blockIdx.y, b = blockIdx.z;
  int q0 = blockIdx.x * 256 + wv * 64;  // wave owns 64 q rows
  int kspan = NN / splits;

  short8 qf[4];
#pragma unroll
  for (int f = 0; f < 4; f++)
    qf[f] = *(const short8*)(Qb + ((size_t)b * NN + q0 + f * 16 + l15) * ICH +
                             quad * 8);

  float4v o[4][2];
#pragma unroll
  for (int f = 0; f < 4; f++) {
    o[f][0] = (float4v){0.f, 0.f, 0.f, 0.f};
    o[f][1] = (float4v){0.f, 0.f, 0.f, 0.f};
  }
  float lsp[4] = {0.f, 0.f, 0.f, 0.f};

  const ushort_t* Kbb = Kb + (size_t)b * NN * ICH;
  const ushort_t* Vtb = Vt + (size_t)b * ICH * NN;
  int mbeg = s * kspan, mend = mbeg + kspan;

  const bool lowq = (quad < 2);
  const bool evenq = ((quad & 1) == 0);

  for (int m0 = mbeg; m0 < mend; m0 += 32) {
    const ushort_t* kp = Kbb + (size_t)(m0 + l15) * ICH + quad * 8;
    short8 kf0 = *(const short8*)(kp);
    short8 kf1 = *(const short8*)(kp + 16 * ICH);
    const ushort_t* vp = Vtb + (size_t)l15 * NN + m0 + quad * 8;
    short8 vf0 = *(const short8*)(vp);
    short8 vf1 = *(const short8*)(vp + 16 * NN);

#pragma unroll
    for (int f = 0; f < 4; f++) {
      float4v z = {0.f, 0.f, 0.f, 0.f};
      float4v st0 = __builtin_amdgcn_mfma_f32_16x16x32_bf16(kf0, qf[f], z, 0, 0, 0);
      float4v st1 = __builtin_amdgcn_mfma_f32_16x16x32_bf16(kf1, qf[f], z, 0, 0, 0);

      float p0[4], p1[4];
#pragma unroll
      for (int r = 0; r < 4; r++) {
        p0[r] = __expf(fminf(st0[r], 60.f));
        p1[r] = __expf(fminf(st1[r], 60.f));
        lsp[f] += p0[r] + p1[r];
      }
      unsigned d0 = pack2(p0[0], p0[1]);
      unsigned d1 = pack2(p0[2], p0[3]);
      unsigned d2 = pack2(p1[0], p1[1]);
      unsigned d3 = pack2(p1[2], p1[3]);
      unsigned e0 = lowq ? d2 : d0, e1 = lowq ? d3 : d1;
      unsigned k0 = lowq ? d0 : d2, k1 = lowq ? d1 : d3;
      unsigned r0 = (unsigned)__shfl_xor((int)e0, 32, 64);
      unsigned r1 = (unsigned)__shfl_xor((int)e1, 32, 64);
      unsigned a0 = lowq ? k0 : r0;
      unsigned a1 = lowq ? k1 : r1;
      unsigned a2 = lowq ? r0 : k0;
      unsigned a3 = lowq ? r1 : k1;
      unsigned f0 = evenq ? a2 : a0, f1 = evenq ? a3 : a1;
      unsigned g0 = evenq ? a0 : a2, g1 = evenq ? a1 : a3;
      unsigned s0w = (unsigned)__shfl_xor((int)f0, 16, 64);
      unsigned s1w = (unsigned)__shfl_xor((int)f1, 16, 64);
      unsigned w0 = evenq ? g0 : s0w;
      unsigned w1 = evenq ? g1 : s1w;
      unsigned w2 = evenq ? s0w : g0;
      unsigned w3 = evenq ? s1w : g1;

      union { unsigned u[4]; short8 s8; } pu;
      pu.u[0] = w0; pu.u[1] = w1; pu.u[2] = w2; pu.u[3] = w3;
      short8 pf = pu.s8;

      o[f][0] = __builtin_amdgcn_mfma_f32_16x16x32_bf16(pf, vf0, o[f][0], 0, 0, 0);
      o[f][1] = __builtin_amdgcn_mfma_f32_16x16x32_bf16(pf, vf1, o[f][1], 0, 0, 0);
    }
  }

  size_t base = (size_t)(b * splits + s) * NN;
#pragma unroll
  for (int f = 0; f < 4; f++) {
    float v = lsp[f];
    v += __shfl_xor(v, 16, 64);
    v += __shfl_xor(v, 32, 64);
    if (quad == 0) LS[base + q0 + f * 16 + l15] = v;
#pragma unroll
    for (int r = 0; r < 4; r++) {
      int q = q0 + f * 16 + quad * 4 + r;
      float* op = OP + (base + q) * ICH;
      op[l15] = o[f][0][r];
      op[16 + l15] = o[f][1][r];
    }
  }
}

// ---------------------------------------------------------------------------
// Kernel 3: combine splits + wz + BN stat partials (R8/R10-proven).
// ---------------------------------------------------------------------------
__global__ __launch_bounds__(256) void wz_kernel(
    const float* __restrict__ OP, const float* __restrict__ LS,
    const float* __restrict__ wz_w, const float* __restrict__ wz_b,
    float* __restrict__ WY, float* __restrict__ SP, int splits) {
  __shared__ float yl[64 * 36];
  __shared__ float lsum[64];
  __shared__ float red1[256], red2[256];

  int b = blockIdx.y, n0 = blockIdx.x * 64, t = threadIdx.x;
  int blkid = b * 64 + blockIdx.x;

  if (t < 64) {
    float ssum = 0.f;
    for (int sp = 0; sp < splits; sp++)
      ssum += LS[(size_t)(b * splits + sp) * NN + n0 + t];
    lsum[t] = ssum;
  }
  __syncthreads();
#pragma unroll
  for (int it = 0; it < 8; it++) {
    int lin = it * 256 + t;
    int i = lin & 31, dn = lin >> 5;
    float sacc = 0.f;
    for (int sp = 0; sp < splits; sp++)
      sacc += OP[((size_t)(b * splits + sp) * NN + n0 + dn) * ICH + i];
    yl[dn * 36 + i] = sacc / lsum[dn];
  }
  __syncthreads();

  int c = t >> 2, sub = t & 3;
  float4 w4[8];
#pragma unroll
  for (int j = 0; j < 8; j++) w4[j] = ((const float4*)(wz_w + c * ICH))[j];
  float bc = wz_b[c];
  float s1 = 0.f, s2 = 0.f;
#pragma unroll
  for (int d = 0; d < 16; d++) {
    int dn = sub * 16 + d;
    const float4* y4 = (const float4*)(yl + dn * 36);
    float acc = bc;
#pragma unroll
    for (int j = 0; j < 8; j++) {
      float4 y = y4[j];
      acc += w4[j].x * y.x + w4[j].y * y.y + w4[j].z * y.z + w4[j].w * y.w;
    }
    WY[((size_t)(b * CC + c)) * NN + n0 + dn] = acc;
    s1 += acc;
    s2 += acc * acc;
  }
  red1[t] = s1;
  red2[t] = s2;
  __syncthreads();
  if (t < 64) {
    float a1 = red1[t * 4] + red1[t * 4 + 1] + red1[t * 4 + 2] + red1[t * 4 + 3];
    float a2 = red2[t * 4] + red2[t * 4 + 1] + red2[t * 4 + 2] + red2[t * 4 + 3];
    SP[(size_t)blkid * 64 + t] = a1;
    SP[16384 + (size_t)blkid * 64 + t] = a2;
  }
}

// ---------------------------------------------------------------------------
// Kernel 4: final BN stats, one block per channel (R10-proven).
// ---------------------------------------------------------------------------
__global__ __launch_bounds__(256) void stats_kernel(
    const float* __restrict__ SP, const float* __restrict__ gamma,
    const float* __restrict__ beta, float* __restrict__ AB) {
  __shared__ double r1[256], r2[256];
  int c = blockIdx.x, t = threadIdx.x;
  r1[t] = (double)SP[(size_t)t * 64 + c];
  r2[t] = (double)SP[16384 + (size_t)t * 64 + c];
  __syncthreads();
  for (int off = 128; off > 0; off >>= 1) {
    if (t < off) {
      r1[t] += r1[t + off];
      r2[t] += r2[t + off];
    }
    __syncthreads();
  }
  if (t == 0) {
    double inv = 1.0 / (double)(BB * NN);
    double mean = r1[0] * inv;
    double var = r2[0] * inv - mean * mean;
    if (var < 0.0) var = 0.0;
    double rstd = 1.0 / sqrt(var + 1e-5);
    float A = gamma[c] * (float)rstd;
    AB[c] = A;
    AB[64 + c] = beta[c] - (float)mean * A;
  }
}

// ---------------------------------------------------------------------------
// Kernel 5: normalize + residual -> fp32 out (B,C,N)  (R8/R10-proven)
// ---------------------------------------------------------------------------
__global__ __launch_bounds__(256) void norm_kernel(
    const float* __restrict__ WY, const float* __restrict__ AB,
    const float* __restrict__ xthis, float* __restrict__ out) {
  __shared__ float xl[64 * 65];
  __shared__ float abr[128];
  int b = blockIdx.y, n0 = blockIdx.x * 64, t = threadIdx.x;
  if (t < 128) abr[t] = AB[t];
#pragma unroll
  for (int it = 0; it < 16; it++) {
    int lin = it * 256 + t;
    int c = lin & 63, dn = lin >> 6;
    xl[dn * 65 + c] = xthis[((size_t)(n0 + dn) * BB + b) * CC + c];
  }
  __syncthreads();
#pragma unroll
  for (int it = 0; it < 16; it++) {
    int lin = it * 256 + t;
    int c = lin >> 6, dn = lin & 63;
    size_t idx = ((size_t)(b * CC + c)) * NN + n0 + dn;
    out[idx] = WY[idx] * abr[c] + abr[64 + c] + xl[dn * 65 + c];
  }
}

// ---------------------------------------------------------------------------
extern "C" void kernel_launch(void* const* d_in, const int* in_sizes, int n_in,
                              void* d_out, int out_size, void* d_ws,
                              size_t ws_size, hipStream_t stream) {
  const float* x_this = (const float*)d_in[0];
  const float* x_other = (const float*)d_in[1];
  const float* g_w = (const float*)d_in[2];
  const float* g_b = (const float*)d_in[3];
  const float* th_w = (const float*)d_in[4];
  const float* th_b = (const float*)d_in[5];
  const float* ph_w = (const float*)d_in[6];
  const float* ph_b = (const float*)d_in[7];
  const float* wz_w = (const float*)d_in[8];
  const float* wz_b = (const float*)d_in[9];
  const float* gamma = (const float*)d_in[10];
  const float* beta = (const float*)d_in[11];
  float* out = (float*)d_out;

  float* ws = (float*)d_ws;
  ushort_t* Qb = (ushort_t*)(ws + OFF_QB);
  ushort_t* Kb = (ushort_t*)(ws + OFF_KB);
  ushort_t* Vt = (ushort_t*)(ws + OFF_VT);

  int splits = 8;
  while (splits > 1 &&
         ws_size < (size_t)(786432 + (size_t)splits * 540672 + 32768 +
                            1048576 + 128) * 4)
    splits >>= 1;
  float* OP = ws + OFF_OP;
  float* LS = OP + (size_t)splits * 524288;
  float* SP = LS + (size_t)splits * 16384;
  float* WY = SP + 32768;
  float* AB = WY + 1048576;

  hipLaunchKernelGGL(proj_kernel, dim3(NN / 64, BB, 3), dim3(256), 0, stream,
                     x_this, x_other, g_w, g_b, th_w, th_b, ph_w, ph_b,
                     Qb, Kb, Vt);
  hipLaunchKernelGGL(attn_kernel, dim3(NN / 256, splits, BB), dim3(256), 0,
                     stream, Qb, Kb, Vt, OP, LS, splits);
  hipLaunchKernelGGL(wz_kernel, dim3(NN / 64, BB), dim3(256), 0, stream,
                     OP, LS, wz_w, wz_b, WY, SP, splits);
  hipLaunchKernelGGL(stats_kernel, dim3(CC), dim3(256), 0, stream,
                     SP, gamma, beta, AB);
  hipLaunchKernelGGL(norm_kernel, dim3(NN / 64, BB), dim3(256), 0, stream,
                     WY, AB, x_this, out);
}